// Round 4
// baseline (213.966 us; speedup 1.0000x reference)
//
#include <hip/hip_runtime.h>

typedef float v2f __attribute__((ext_vector_type(2)));

// Force packed fp32 (full-rate, 2 elems/inst on CDNA2+). Operands are 8B
// vectors -> VGPR pairs with the "v" constraint.
__device__ __forceinline__ v2f pk_fma(v2f a, v2f b, v2f c) {
    v2f d;
    asm("v_pk_fma_f32 %0, %1, %2, %3" : "=v"(d) : "v"(a), "v"(b), "v"(c));
    return d;
}
__device__ __forceinline__ v2f pk_mul(v2f a, v2f b) {
    v2f d;
    asm("v_pk_mul_f32 %0, %1, %2" : "=v"(d) : "v"(a), "v"(b));
    return d;
}

// out = (tanh(100(x1-0.1)) - tanh(100(x1+0.1)) + 2)/2
//     = 1 + 1/(E+1) - 1/(E*e^-40 + 1),  E = e^{200(x1+0.1)}
// One v_exp_f32 + two v_rcp_f32. Saturates correctly for +-inf; NaN -> NaN.
__device__ __forceinline__ float band(float x1) {
    float E  = __builtin_amdgcn_exp2f(fmaf(288.539008f, x1, 28.8539008f)); // 200*log2e
    float Eu = E * 4.248354255291589e-18f;   // e^-40
    return 1.0f + __builtin_amdgcn_rcpf(E + 1.0f) - __builtin_amdgcn_rcpf(Eu + 1.0f);
}

// 16 elements/thread: 8 coalesced float4 loads (batched up-front for MLP),
// packed 5-op recurrence step, nontemporal float2 stores.
__global__ void __launch_bounds__(256)
dynsys_kernel(const float4* __restrict__ x, const float* __restrict__ ws,
              v2f* __restrict__ out, int T) {
    int i = blockIdx.x * 256 + threadIdx.x;
    if (i >= T) return;

    // wn[k] = {-w,-w}; recurrence: nx1 = x1 - 0.1*((x0^2-1)*x0 - w*x1)
    v2f wn[10];
#pragma unroll
    for (int k = 0; k < 10; ++k) { float v = -ws[k]; wn[k] = (v2f){v, v}; }
    const v2f mone = {-1.0f, -1.0f};
    const v2f cn01 = {-0.1f, -0.1f};

    float4 ld[8];
#pragma unroll
    for (int k = 0; k < 8; ++k) ld[k] = x[i + k * T];   // 8 loads in flight

#pragma unroll
    for (int k = 0; k < 8; ++k) {
        v2f a0 = {ld[k].x, ld[k].z};
        v2f a1 = {ld[k].y, ld[k].w};
#pragma unroll
        for (int s = 0; s < 10; ++s) {
            v2f na0 = pk_fma(cn01, a1, a0);   // x0 - 0.1*x1
            v2f t   = pk_fma(a0, a0, mone);   // x0^2 - 1
            v2f u   = pk_mul(a0, t);          // x0^3 - x0
            v2f d   = pk_fma(wn[s], a1, u);   // x0^3 - x0 - w*x1
            a1      = pk_fma(cn01, d, a1);    // x1 - 0.1*d
            a0      = na0;
        }
        v2f r = {band(a1.x), band(a1.y)};
        __builtin_nontemporal_store(r, &out[i + k * T]);  // out never re-read
    }
}

extern "C" void kernel_launch(void* const* d_in, const int* in_sizes, int n_in,
                              void* d_out, int out_size, void* d_ws, size_t ws_size,
                              hipStream_t stream) {
    const float4* x  = (const float4*)d_in[0];   // [B,2] f32 = B/2 float4s
    const float*  ws = (const float*)d_in[1];    // [10] f32
    v2f* out = (v2f*)d_out;                      // [B] f32 = B/2 float2s

    int n4 = in_sizes[0] / 4;                    // float4 count = B/2
    int T  = n4 / 8;                             // 8 float4s (16 elems) per thread
    int blocks = (T + 255) / 256;
    dynsys_kernel<<<blocks, 256, 0, stream>>>(x, ws, out, T);
}

// Round 5
// 208.620 us; speedup vs baseline: 1.0256x; 1.0256x over previous
//
#include <hip/hip_runtime.h>

typedef float v2f __attribute__((ext_vector_type(2)));

// Forced packed fp32 (full-rate on CDNA).
__device__ __forceinline__ v2f pk_fma(v2f a, v2f b, v2f c) {
    v2f d;
    asm("v_pk_fma_f32 %0, %1, %2, %3" : "=v"(d) : "v"(a), "v"(b), "v"(c));
    return d;
}
__device__ __forceinline__ v2f pk_mul(v2f a, v2f b) {
    v2f d;
    asm("v_pk_mul_f32 %0, %1, %2" : "=v"(d) : "v"(a), "v"(b));
    return d;
}

// band(x1) = (tanh(100(x1-0.1)) - tanh(100(x1+0.1)) + 2)/2  -- even in x1.
// Exact rewrite: 1 - sinh(20)/(cosh(200 x1) + cosh(20)); with F=e^{200|x1|}>=1
// the 1/F half of cosh is <=0.5 vs K~2.4e8 -> drop it:
//   out = 1 - S * rcp(0.5*F + K),  S=sinh(20), K=cosh(20)
// One v_exp_f32 + one v_rcp_f32. F->inf => out=1 (correct saturation); NaN->NaN.
__device__ __forceinline__ float band(float x1) {
    const float S = 2.4258257e8f;   // sinh(20)
    const float K = 2.4258257e8f;   // cosh(20) (== sinh(20) in fp32)
    float t = __builtin_fabsf(x1);
    float F = __builtin_amdgcn_exp2f(288.53900817779268f * t);  // e^{200|x1|}
    float r = __builtin_amdgcn_rcpf(fmaf(0.5f, F, K));
    return fmaf(-S, r, 1.0f);
}

// 4 elements/thread: 2 dense float4 load streams, packed 5-op step, nt stores.
// Grid is exact (B/4 threads), no bounds guard.
__global__ void __launch_bounds__(256)
dynsys_kernel(const float4* __restrict__ x, const float* __restrict__ ws,
              v2f* __restrict__ out, int T) {
    int i = blockIdx.x * 256 + threadIdx.x;

    // wn[k] = {-w,-w}; step: nx1 = x1 - 0.1*((x0^2-1)*x0 - w*x1)
    v2f wn[10];
#pragma unroll
    for (int k = 0; k < 10; ++k) { float v = -ws[k]; wn[k] = (v2f){v, v}; }
    const v2f mone = {-1.0f, -1.0f};
    const v2f cn01 = {-0.1f, -0.1f};

    float4 va = x[i];
    float4 vb = x[i + T];

    v2f a0 = {va.x, va.z}, a1 = {va.y, va.w};
    v2f b0 = {vb.x, vb.z}, b1 = {vb.y, vb.w};

#pragma unroll
    for (int s = 0; s < 10; ++s) {
        v2f na0 = pk_fma(cn01, a1, a0);
        v2f ta  = pk_fma(a0, a0, mone);
        v2f ua  = pk_mul(a0, ta);
        v2f da  = pk_fma(wn[s], a1, ua);
        a1      = pk_fma(cn01, da, a1);
        a0      = na0;

        v2f nb0 = pk_fma(cn01, b1, b0);
        v2f tb  = pk_fma(b0, b0, mone);
        v2f ub  = pk_mul(b0, tb);
        v2f db  = pk_fma(wn[s], b1, ub);
        b1      = pk_fma(cn01, db, b1);
        b0      = nb0;
    }

    v2f ra = {band(a1.x), band(a1.y)};
    v2f rb = {band(b1.x), band(b1.y)};
    __builtin_nontemporal_store(ra, &out[i]);
    __builtin_nontemporal_store(rb, &out[i + T]);
}

extern "C" void kernel_launch(void* const* d_in, const int* in_sizes, int n_in,
                              void* d_out, int out_size, void* d_ws, size_t ws_size,
                              hipStream_t stream) {
    const float4* x  = (const float4*)d_in[0];   // [B,2] f32 = B/2 float4s
    const float*  ws = (const float*)d_in[1];    // [10] f32
    v2f* out = (v2f*)d_out;                      // [B] f32 = B/2 float2s

    int n4 = in_sizes[0] / 4;                    // B/2 float4s
    int T  = n4 / 2;                             // 2 float4s (4 elems) per thread
    int blocks = T / 256;                        // B=16777216 -> exact fit
    dynsys_kernel<<<blocks, 256, 0, stream>>>(x, ws, out, T);
}

// Round 7
// 203.984 us; speedup vs baseline: 1.0489x; 1.0227x over previous
//
#include <hip/hip_runtime.h>

typedef float v2f __attribute__((ext_vector_type(2)));
typedef float v4f __attribute__((ext_vector_type(4)));   // builtin-friendly float4

// Forced packed fp32 (full-rate on CDNA).
__device__ __forceinline__ v2f pk_fma(v2f a, v2f b, v2f c) {
    v2f d;
    asm("v_pk_fma_f32 %0, %1, %2, %3" : "=v"(d) : "v"(a), "v"(b), "v"(c));
    return d;
}
__device__ __forceinline__ v2f pk_mul(v2f a, v2f b) {
    v2f d;
    asm("v_pk_mul_f32 %0, %1, %2" : "=v"(d) : "v"(a), "v"(b));
    return d;
}

// band(x1) = (tanh(100(x1-0.1)) - tanh(100(x1+0.1)) + 2)/2  (even in x1)
//          = 1 - S * rcp(0.5*e^{200|x1|} + K),  S=sinh(20)==cosh(20) in fp32
// One v_exp_f32 + one v_rcp_f32. inf -> 1 (correct saturation); NaN -> NaN.
__device__ __forceinline__ float band(float x1) {
    const float S = 2.4258257e8f;
    float t = __builtin_fabsf(x1);
    float F = __builtin_amdgcn_exp2f(288.53900817779268f * t);  // e^{200|x1|}
    float r = __builtin_amdgcn_rcpf(fmaf(0.5f, F, S));
    return fmaf(-S, r, 1.0f);
}

// Copy-shaped: persistent grid-stride loop, 8 dense 16B NT load streams per
// iteration (128 B/thread in flight), packed 5-op recurrence, NT 8B stores.
// Coverage exact: 2048 blk * 256 thr * 8 streams * 2 iters = 2^23 float4s = B/2.
__global__ void __launch_bounds__(256)
dynsys_kernel(const v4f* __restrict__ x, const float* __restrict__ ws,
              v2f* __restrict__ out, int n4) {
    const int tid    = blockIdx.x * 256 + threadIdx.x;
    const int nthr   = gridDim.x * 256;        // dense-stream stride
    const int per_it = nthr * 8;               // float4s consumed per iteration

    // step: nx1 = x1 - 0.1*((x0^2-1)*x0 - w*x1) ; wn[k] = {-w,-w}
    v2f wn[10];
#pragma unroll
    for (int k = 0; k < 10; ++k) { float v = -ws[k]; wn[k] = (v2f){v, v}; }
    const v2f mone = {-1.0f, -1.0f};
    const v2f cn01 = {-0.1f, -0.1f};

    for (int base = tid; base < n4; base += per_it) {
        v4f ld[8];
#pragma unroll
        for (int k = 0; k < 8; ++k)
            ld[k] = __builtin_nontemporal_load(&x[base + k * nthr]);

#pragma unroll
        for (int k = 0; k < 8; ++k) {
            v2f a0 = {ld[k].x, ld[k].z};
            v2f a1 = {ld[k].y, ld[k].w};
#pragma unroll
            for (int s = 0; s < 10; ++s) {
                v2f na0 = pk_fma(cn01, a1, a0);   // x0 - 0.1*x1
                v2f t   = pk_fma(a0, a0, mone);   // x0^2 - 1
                v2f u   = pk_mul(a0, t);          // x0^3 - x0
                v2f d   = pk_fma(wn[s], a1, u);   // ... - w*x1
                a1      = pk_fma(cn01, d, a1);    // x1 - 0.1*d
                a0      = na0;
            }
            v2f r = {band(a1.x), band(a1.y)};
            __builtin_nontemporal_store(r, &out[base + k * nthr]);
        }
    }
}

extern "C" void kernel_launch(void* const* d_in, const int* in_sizes, int n_in,
                              void* d_out, int out_size, void* d_ws, size_t ws_size,
                              hipStream_t stream) {
    const v4f*  x  = (const v4f*)d_in[0];    // [B,2] f32 = B/2 float4s
    const float* ws = (const float*)d_in[1]; // [10] f32
    v2f* out = (v2f*)d_out;                  // [B] f32 = B/2 float2s

    int n4 = in_sizes[0] / 4;                // B/2 = 2^23 float4s
    // 2048 blocks * 256 thr = 2^19 threads; *8 streams *2 iters = 2^23 exact.
    dynsys_kernel<<<2048, 256, 0, stream>>>(x, ws, out, n4);
}